// Round 1
// baseline (559.399 us; speedup 1.0000x reference)
//
#include <hip/hip_runtime.h>

typedef unsigned short u16;
typedef unsigned int u32;

typedef __bf16 bf16x8 __attribute__((ext_vector_type(8)));
typedef float f32x4 __attribute__((ext_vector_type(4)));
typedef u16 u16x8 __attribute__((ext_vector_type(8)));

#define TSEQ 4096
#define DDIM 1024
#define NB 4
#define EPSV 1e-6f
// bounce-buffer row pitch in u16 (272 B = 17*16 -> rows stay 16B-aligned, banks rotate)
#define CPITCH 136
// 256^2 epilogue bounce pitch (u16): 528 B rows, 16B-aligned, banks rotate by 4
#define EPITCH 264

__device__ __forceinline__ u16 f2b(float f) {
    union { float f; u32 u; } v; v.f = f;
    u32 r = v.u + 0x7FFFu + ((v.u >> 16) & 1u);
    return (u16)(r >> 16);
}
__device__ __forceinline__ float b2f(u16 h) {
    union { u32 u; float f; } v; v.u = ((u32)h) << 16; return v.f;
}
__device__ __forceinline__ u16 f2h(float f) {
    union { _Float16 h; u16 u; } v; v.h = (_Float16)f; return v.u;
}
__device__ __forceinline__ float h2f(u16 u) {
    union { u16 u; _Float16 h; } v; v.u = u; return (float)v.h;
}

// ---------------- merged prep: x->bf16, W->bf16 concat, bias concat, denom zero ----
__global__ __launch_bounds__(256) void k_prep(
    const float* __restrict__ x,
    const float* __restrict__ wq, const float* __restrict__ wk,
    const float* __restrict__ wv, const float* __restrict__ wa,
    const float* __restrict__ bq, const float* __restrict__ bk,
    const float* __restrict__ bv, const float* __restrict__ ba,
    u16* __restrict__ xw, u16* __restrict__ wcat, float* __restrict__ bcat,
    float* __restrict__ denom) {
    int bid = blockIdx.x, tid = threadIdx.x;
    if (bid < 1024) {
        size_t base = (size_t)bid * 4096 + tid;
#pragma unroll
        for (int k = 0; k < 16; ++k) {
            size_t f4 = base + k * 256;
            float4 f = ((const float4*)x)[f4];
            ushort4 u;
            u.x = f2b(f.x); u.y = f2b(f.y); u.z = f2b(f.z); u.w = f2b(f.w);
            *(ushort4*)(xw + f4 * 4) = u;
        }
    } else if (bid < 1280) {
        size_t base = (size_t)(bid - 1024) * 4096 + tid;
#pragma unroll
        for (int k = 0; k < 16; ++k) {
            size_t f4 = base + k * 256;
            int sel = (int)(f4 >> 18);
            const float* src = (sel == 0) ? wq : (sel == 1) ? wk : (sel == 2) ? wv : wa;
            float4 f = ((const float4*)src)[f4 & 262143];
            ushort4 u;
            u.x = f2b(f.x); u.y = f2b(f.y); u.z = f2b(f.z); u.w = f2b(f.w);
            *(ushort4*)(wcat + f4 * 4) = u;
        }
    } else if (bid == 1280) {
#pragma unroll
        for (int c = 0; c < 16; ++c) {
            int j = c * 256 + tid;
            int sel = j >> 10;
            const float* src = (sel == 0) ? bq : (sel == 1) ? bk : (sel == 2) ? bv : ba;
            bcat[j] = src[j & 1023];
        }
    } else {
        float4 z = {0.f, 0.f, 0.f, 0.f};
#pragma unroll
        for (int k = 0; k < 16; ++k)
            ((float4*)denom)[k * 256 + tid] = z;
    }
}

// ---------------- GEMM core helpers (used by k_scores / k_num, 128^2 structure) ----
__device__ __forceinline__ void stage_k(u16* __restrict__ dst, const char* __restrict__ base,
                                        int ld2, int kbyte, int wid, int lane) {
#pragma unroll
    for (int c = 0; c < 4; ++c) {
        const char* g = base + c * 8 * ld2 + kbyte;
        char* l = (char*)dst + (wid * 32 + c * 8) * 128 + lane * 16;
        __builtin_amdgcn_global_load_lds((const __attribute__((address_space(1))) u32*)g,
                                         (__attribute__((address_space(3))) u32*)l, 16, 0, 0);
    }
}

__device__ __forceinline__ void mma_tile(const u16* __restrict__ As, const u16* __restrict__ Bs,
                                         f32x4 acc[4][4], int wm, int wn, int quad, int l15) {
#pragma unroll
    for (int kk = 0; kk < 64; kk += 32) {
        int cg = (kk >> 3) + quad;
        bf16x8 a[4], b[4];
#pragma unroll
        for (int i = 0; i < 4; ++i) {
            int arow = wm * 64 + i * 16 + l15;
            int brow = wn * 64 + i * 16 + l15;
            a[i] = *(const bf16x8*)(As + arow * 64 + ((cg ^ (arow & 7)) << 3));
            b[i] = *(const bf16x8*)(Bs + brow * 64 + ((cg ^ (brow & 7)) << 3));
        }
#pragma unroll
        for (int i = 0; i < 4; ++i)
#pragma unroll
            for (int j = 0; j < 4; ++j)
                acc[i][j] = __builtin_amdgcn_mfma_f32_16x16x32_bf16(a[i], b[j], acc[i][j], 0, 0, 0);
    }
}

// ---------------- fused QKVA projection GEMM: 256^2 tile, 8-wave, 8-phase ----------
// Round 12: ported to the 256^2 8-phase schedule (T2 swizzle + T3 phase-split +
// T4 counted vmcnt + T5 setprio). 512 threads = 2x4 waves, per-wave C = 128x64.
// LDS 128 KiB: A/B double-buffered K-tiles (BK=64), each split into two 128-row
// halves. Per K-tile 4 phases; each phase: 12 ds_read_b128 (one C-quadrant's
// frags) + one half-tile stage (2 global_load_lds) + barrier + MFMA cluster.
// Stage ledger (tile t): q0->A[t+1]h1, q1->B[t+1]h1, q2->A[t+2]h0 (overwrites
// A[t]h0, dead after q1's end barrier), q3->B[t+2]h0, then vmcnt(4) -- leaves
// exactly {A[t+2]h0,B[t+2]h0} in flight, guarantees tile t+1 landed. Never
// vmcnt(0) in the main loop.
#define STG_A(d, h, t) do { \
    const char* _g = gAp + ((h) * 262144 + wid * 32768 + (t) * 128); \
    char* _l = lA + ((d) * 32768 + (h) * 16384); \
    __builtin_amdgcn_global_load_lds((const __attribute__((address_space(1))) u32*)_g, \
        (__attribute__((address_space(3))) u32*)_l, 16, 0, 0); \
    __builtin_amdgcn_global_load_lds((const __attribute__((address_space(1))) u32*)(_g + 16384), \
        (__attribute__((address_space(3))) u32*)(_l + 1024), 16, 0, 0); \
  } while (0)

#define STG_B(d, h, t) do { \
    const char* _g = gBp + ((h) * 262144 + wid * 32768 + (t) * 128); \
    char* _l = lB + ((d) * 32768 + (h) * 16384); \
    __builtin_amdgcn_global_load_lds((const __attribute__((address_space(1))) u32*)_g, \
        (__attribute__((address_space(3))) u32*)_l, 16, 0, 0); \
    __builtin_amdgcn_global_load_lds((const __attribute__((address_space(1))) u32*)(_g + 16384), \
        (__attribute__((address_space(3))) u32*)(_l + 1024), 16, 0, 0); \
  } while (0)

#define NOP_ ((void)0)
#define VM4_ asm volatile("s_waitcnt vmcnt(4)" ::: "memory")
#define VM0_ asm volatile("s_waitcnt vmcnt(0)" ::: "memory")

#define PHASE(d, qa, qb, STAGE_STMT, VM_STMT) do { \
    const u16* _Ah = As + (d) * 16384 + (qa) * 8192; \
    const u16* _Bh = Bs + (d) * 16384 + (qb) * 8192; \
    bf16x8 _a[4][2]; bf16x8 _b[2][2]; \
    _Pragma("unroll") \
    for (int _i = 0; _i < 4; ++_i) { \
      int _ra = wm * 64 + _i * 16 + l15; \
      const u16* _p = _Ah + _ra * 64; \
      _a[_i][0] = *(const bf16x8*)(_p + ((quad ^ (_ra & 7)) << 3)); \
      _a[_i][1] = *(const bf16x8*)(_p + (((quad + 4) ^ (_ra & 7)) << 3)); \
    } \
    _Pragma("unroll") \
    for (int _j = 0; _j < 2; ++_j) { \
      int _rb = wn * 32 + _j * 16 + l15; \
      const u16* _p = _Bh + _rb * 64; \
      _b[_j][0] = *(const bf16x8*)(_p + ((quad ^ (_rb & 7)) << 3)); \
      _b[_j][1] = *(const bf16x8*)(_p + (((quad + 4) ^ (_rb & 7)) << 3)); \
    } \
    STAGE_STMT; \
    __builtin_amdgcn_s_barrier(); \
    asm volatile("s_waitcnt lgkmcnt(0)" ::: "memory"); \
    __builtin_amdgcn_s_setprio(1); \
    _Pragma("unroll") \
    for (int _kk = 0; _kk < 2; ++_kk) \
      _Pragma("unroll") \
      for (int _i = 0; _i < 4; ++_i) \
        _Pragma("unroll") \
        for (int _j = 0; _j < 2; ++_j) \
          acc[(qa) * 4 + _i][(qb) * 2 + _j] = __builtin_amdgcn_mfma_f32_16x16x32_bf16( \
              _a[_i][_kk], _b[_j][_kk], acc[(qa) * 4 + _i][(qb) * 2 + _j], 0, 0, 0); \
    __builtin_amdgcn_s_setprio(0); \
    VM_STMT; \
    __builtin_amdgcn_s_barrier(); \
  } while (0)

__global__ __launch_bounds__(512, 2) void k_gemm_qkva(
    const u16* __restrict__ xw, const u16* __restrict__ wcat, const float* __restrict__ bcat,
    u16* __restrict__ qb, u16* __restrict__ kb, u16* __restrict__ vT, u16* __restrict__ gA,
    float* __restrict__ part) {
    __shared__ __align__(16) char smem[131072];  // A[2][2][128][64] | B[2][2][128][64]
    u16* As = (u16*)smem;
    u16* Bs = (u16*)(smem + 65536);
    int tid = threadIdx.x;
    int wid = tid >> 6, lane = tid & 63;
    int wm = wid >> 2, wn = wid & 3;          // 2 x 4 wave grid
    int quad = lane >> 4, l15 = lane & 15;
    int g8 = lane >> 3, hx = (lane & 7) ^ g8;
    size_t m0 = (size_t)blockIdx.x * 256, n0 = (size_t)blockIdx.y * 256;  // m fastest (XCD pin)
    const char* gAp = (const char*)xw + (m0 + g8) * 2048 + hx * 16;
    const char* gBp = (const char*)wcat + (n0 + g8) * 2048 + hx * 16;
    char* lA = smem + wid * 2048 + lane * 16;
    char* lB = smem + 65536 + wid * 2048 + lane * 16;

    f32x4 acc[8][4] = {};
    // prologue: tile0 fully + tile1 h0 halves (12 loads); vmcnt(4) -> tile0 landed,
    // {A1h0,B1h0} in flight == steady-state invariant.
    STG_A(0, 0, 0); STG_A(0, 1, 0);
    STG_B(0, 0, 0); STG_B(0, 1, 0);
    STG_A(1, 0, 1); STG_B(1, 0, 1);
    VM4_;
    __builtin_amdgcn_s_barrier();

#pragma unroll 2
    for (int t = 0; t < 14; ++t) {
        int d = t & 1, dn = d ^ 1;
        PHASE(d, 0, 0, STG_A(dn, 1, t + 1), NOP_);
        PHASE(d, 0, 1, STG_B(dn, 1, t + 1), NOP_);
        PHASE(d, 1, 0, STG_A(d, 0, t + 2), NOP_);
        PHASE(d, 1, 1, STG_B(d, 0, t + 2), VM4_);
    }
    // t = 14 (tail: no t+2 stages; drain so tile 15 is resident)
    PHASE(0, 0, 0, STG_A(1, 1, 15), NOP_);
    PHASE(0, 0, 1, STG_B(1, 1, 15), NOP_);
    PHASE(0, 1, 0, NOP_, NOP_);
    PHASE(0, 1, 1, NOP_, VM0_);
    // t = 15 (no stages in flight)
    PHASE(1, 0, 0, NOP_, NOP_);
    PHASE(1, 0, 1, NOP_, NOP_);
    PHASE(1, 1, 0, NOP_, NOP_);
    PHASE(1, 1, 1, NOP_, NOP_);

    // ---------------- epilogue: two 128-row bounce rounds through LDS -------------
    int blk = (int)(n0 >> 10), nf0 = (int)(n0 & 1023);
    int bB = (int)(m0 >> 12), t0m = (int)(m0 & 4095);
    float bias[4];
#pragma unroll
    for (int j = 0; j < 4; ++j)
        bias[j] = bcat[n0 + (size_t)((j >> 1) * 128 + wn * 32 + (j & 1) * 16 + l15)];
    u16* Cs = (u16*)smem;

#pragma unroll
    for (int h = 0; h < 2; ++h) {
        if (h) __syncthreads();  // prior round's LDS reads done before overwrite
#pragma unroll
        for (int j = 0; j < 4; ++j) {
            float cs = 0.f;
            int col = (j >> 1) * 128 + wn * 32 + (j & 1) * 16 + l15;
#pragma unroll
            for (int i4 = 0; i4 < 4; ++i4) {
#pragma unroll
                for (int r = 0; r < 4; ++r) {
                    float z = acc[h * 4 + i4][j][r] + bias[j];
                    u16 o;
                    if (blk < 2) {
                        o = f2b(fmaxf(z, 0.f));
                    } else if (blk == 2) {
                        o = f2b(z);
                    } else {
                        float gg = __logf(1.f / (1.f + __expf(-z)) + 1e-6f);
                        o = f2h(gg);
                        cs += gg;
                    }
                    Cs[(wm * 64 + i4 * 16 + quad * 4 + r) * EPITCH + col] = o;
                }
            }
            if (blk == 3) {
                // 64-row chunk column sum (rows h*128 + wm*64 .. +63)
                cs += __shfl_xor(cs, 16, 64);
                cs += __shfl_xor(cs, 32, 64);
                if (quad == 0) {
                    int chunk = (t0m >> 6) + h * 2 + wm;
                    part[((size_t)(bB * 64 + chunk) << 10) + nf0 + col] = cs;
                }
            }
        }
        __syncthreads();
        if (blk != 2) {
            // row-major vectorized store (q / k / gA)
            u16* dst = (blk == 0) ? qb : (blk == 1) ? kb : gA;
            int lr = tid >> 2, c0 = (tid & 3) * 64;
            size_t rowo = (size_t)(m0 + h * 128 + lr) * 1024 + nf0 + c0;
#pragma unroll
            for (int i = 0; i < 8; ++i)
                *(u16x8*)(dst + rowo + i * 8) = *(const u16x8*)(Cs + lr * EPITCH + c0 + i * 8);
        } else {
            // v: read bounce transposed, write vT[b][j][t] coalesced.
            int jc = tid >> 1, th = (tid & 1) * 64;
            size_t rowo = (((size_t)(bB * 1024 + nf0 + jc)) << 12) + t0m + h * 128 + th;
#pragma unroll
            for (int i = 0; i < 8; ++i) {
                u16x8 vv;
#pragma unroll
                for (int e = 0; e < 8; ++e)
                    vv[e] = Cs[(th + i * 8 + e) * EPITCH + jc];
                *(u16x8*)(vT + rowo + i * 8) = vv;
            }
        }
    }
}

// ---------------- gate scan apply (fused suffix-sum of raw chunk partials) ----------
__global__ __launch_bounds__(256) void k_scan_apply(
    const u16* __restrict__ gA, const float* __restrict__ part, u16* __restrict__ kb) {
    int c = blockIdx.x, b = blockIdx.y;
    int col = blockIdx.z * 256 + threadIdx.x;
    float r = 0.f;
    for (int c2 = c + 1; c2 < 64; ++c2)
        r += part[((size_t)(b * 64 + c2) << 10) + col];
    size_t base = (((size_t)(b * TSEQ + c * 64)) << 10) + col;
#pragma unroll 4
    for (int s = 63; s >= 0; --s) {
        size_t ro = base + ((size_t)s << 10);
        r += h2f(gA[ro]);
        kb[ro] = f2b(b2f(kb[ro]) * __expf(r));
    }
}

// ---------------- scores = q @ wk^T (causal), bf16 out + denom atomics ----------------
__global__ __launch_bounds__(256) void k_scores(
    const u16* __restrict__ qb, const u16* __restrict__ wkb,
    u16* __restrict__ scores, float* __restrict__ denom) {
    int bid = blockIdx.x, b = blockIdx.y;
    int xc = bid & 7, idx = bid >> 3;          // idx in [0, 66)
    int rs0 = xc, rs1 = 15 - xc, rs2 = 16 + xc, rs3 = 31 - xc;  // ascending
    int si = 0, rem = idx;
    for (; si < 32; ++si) {
        int n = (rs0 >= si) + (rs1 >= si) + (rs2 >= si) + (rs3 >= si);
        if (rem < n) break;
        rem -= n;
    }
    int ti = rs3, cnt = 0;
    if (rs0 >= si) { if (cnt == rem) ti = rs0; ++cnt; }
    if (rs1 >= si) { if (cnt == rem) ti = rs1; ++cnt; }
    if (rs2 >= si) { if (cnt == rem) ti = rs2; ++cnt; }
    if (rs3 >= si) { if (cnt == rem) ti = rs3; ++cnt; }
    __shared__ __align__(16) char smem[CPITCH * 128 * 2];
    u16* As = (u16*)smem;
    u16* Bs = (u16*)(smem + 16384);
    int tid = threadIdx.x;
    const u16* A = qb + ((size_t)b << 22);
    const u16* Bm = wkb + ((size_t)b << 22);
    int t0 = ti * 128, s0 = si * 128;
    int wid = tid >> 6, lane = tid & 63;
    int wm = wid >> 1, wn = wid & 1, quad = lane >> 4, l15 = lane & 15;
    int hxor = (lane & 7) ^ (lane >> 3);
    const char* baA = (const char*)A + (size_t)(t0 + wid * 32 + (lane >> 3)) * 2048 + hxor * 16;
    const char* baB = (const char*)Bm + (size_t)(s0 + wid * 32 + (lane >> 3)) * 2048 + hxor * 16;
    f32x4 acc[4][4] = {};
#pragma unroll
    for (int k0 = 0; k0 < DDIM; k0 += 64) {
        stage_k(As, baA, 2048, k0 * 2, wid, lane);
        stage_k(Bs, baB, 2048, k0 * 2, wid, lane);
        __syncthreads();
        mma_tile(As, Bs, acc, wm, wn, quad, l15);
        __syncthreads();
    }
    u16* Cs = (u16*)smem;
#pragma unroll
    for (int im = 0; im < 4; ++im) {
#pragma unroll
        for (int r = 0; r < 4; ++r) {
            int trow = t0 + wm * 64 + im * 16 + quad * 4 + r;
            float rs = 0.f;
#pragma unroll
            for (int jn = 0; jn < 4; ++jn) {
                int s = s0 + wn * 64 + jn * 16 + l15;
                float val = acc[im][jn][r];
                if (s > trow) val = 0.f;
                rs += val;
                Cs[(wm * 64 + im * 16 + quad * 4 + r) * CPITCH + wn * 64 + jn * 16 + l15] = f2b(val);
            }
#pragma unroll
            for (int m = 1; m < 16; m <<= 1) rs += __shfl_xor(rs, m, 64);
            if (l15 == 0) atomicAdd(denom + (b << 12) + trow, rs);
        }
    }
    __syncthreads();
    int r = tid >> 1, ch = (tid & 1) * 64;
    size_t rowo = ((size_t)(b * TSEQ + t0 + r) << 12) + s0 + ch;
#pragma unroll
    for (int i = 0; i < 8; ++i)
        *(u16x8*)(scores + rowo + i * 8) = *(const u16x8*)(Cs + r * CPITCH + ch + i * 8);
}

// ---------------- num = scores @ v (causal K bound), divide by denom ----------------
__global__ __launch_bounds__(256) void k_num(
    const u16* __restrict__ scores, const u16* __restrict__ vT,
    const float* __restrict__ denom, float* __restrict__ out) {
    int ji = blockIdx.x, ti = 31 - blockIdx.y, b = blockIdx.z;
    __shared__ __align__(16) u16 As[128 * 64];
    __shared__ __align__(16) u16 Bs[128 * 64];
    int tid = threadIdx.x;
    const u16* A = scores + ((size_t)b << 24);  // [T][T]
    const u16* Bm = vT + ((size_t)b << 22);     // [D][T]
    int t0 = ti * 128, j0 = ji * 128;
    int wid = tid >> 6, lane = tid & 63;
    int wm = wid >> 1, wn = wid & 1, quad = lane >> 4, l15 = lane & 15;
    int hxor = (lane & 7) ^ (lane >> 3);
    const char* pA = (const char*)A + (size_t)(t0 + wid * 32 + (lane >> 3)) * 8192 + hxor * 16;
    const char* pB = (const char*)Bm + (size_t)(j0 + wid * 32 + (lane >> 3)) * 8192 + hxor * 16;
    f32x4 acc[4][4] = {};
    int kmax = (ti + 1) * 128;  // multiple of 128 -> unroll-by-2 safe
    for (int k0 = 0; k0 < kmax; k0 += 128) {
        stage_k(As, pA, 8192, 0, wid, lane);
        stage_k(Bs, pB, 8192, 0, wid, lane);
        __syncthreads();
        mma_tile(As, Bs, acc, wm, wn, quad, l15);
        __syncthreads();
        stage_k(As, pA, 8192, 128, wid, lane);
        stage_k(Bs, pB, 8192, 128, wid, lane);
        __syncthreads();
        mma_tile(As, Bs, acc, wm, wn, quad, l15);
        __syncthreads();
        pA += 256; pB += 256;
    }
#pragma unroll
    for (int im = 0; im < 4; ++im) {
#pragma unroll
        for (int r = 0; r < 4; ++r) {
            int t = t0 + wm * 64 + im * 16 + quad * 4 + r;
            float den = denom[(b << 12) + t] + EPSV;
#pragma unroll
            for (int jn = 0; jn < 4; ++jn) {
                int j = j0 + wn * 64 + jn * 16 + l15;
                out[((size_t)(b * TSEQ + t) << 10) + j] = acc[im][jn][r] / den;
            }
        }
    }
}

// ---------------- workspace layout (bytes) ----------------
static const size_t OFF_Q      = 0;
static const size_t OFF_WK     = 33554432;
static const size_t OFF_VT     = 67108864;
static const size_t OFF_DENOM  = 100663296;
static const size_t OFF_BCAT   = 100728832;
static const size_t OFF_XW     = 100745216;
static const size_t OFF_WCAT   = 134299648;
static const size_t OFF_GA     = 176242688;   // f16: 33.5 MB
static const size_t OFF_PART   = 243351552;
static const size_t OFF_SCORES = OFF_XW;  // 134,217,728 B, overlays dead early region

extern "C" void kernel_launch(void* const* d_in, const int* in_sizes, int n_in,
                              void* d_out, int out_size, void* d_ws, size_t ws_size,
                              hipStream_t stream) {
    const float* x  = (const float*)d_in[0];
    const float* Wq = (const float*)d_in[1];
    const float* bq = (const float*)d_in[2];
    const float* Wk = (const float*)d_in[3];
    const float* bk = (const float*)d_in[4];
    const float* Wv = (const float*)d_in[5];
    const float* bv = (const float*)d_in[6];
    const float* Wa = (const float*)d_in[7];
    const float* ba = (const float*)d_in[8];
    float* out = (float*)d_out;

    char* W = (char*)d_ws;
    u16* qb      = (u16*)(W + OFF_Q);
    u16* wkb     = (u16*)(W + OFF_WK);
    u16* vT      = (u16*)(W + OFF_VT);
    float* denom = (float*)(W + OFF_DENOM);
    float* bcat  = (float*)(W + OFF_BCAT);
    u16* xw      = (u16*)(W + OFF_XW);
    u16* wcat    = (u16*)(W + OFF_WCAT);
    u16* gA      = (u16*)(W + OFF_GA);
    float* part  = (float*)(W + OFF_PART);
    u16* scores  = (u16*)(W + OFF_SCORES);

    k_prep<<<1282, 256, 0, stream>>>(x, Wq, Wk, Wv, Wa, bq, bk, bv, ba, xw, wcat, bcat, denom);

    k_gemm_qkva<<<dim3(64, 16), 512, 0, stream>>>(xw, wcat, bcat, qb, wkb, vT, gA, part);

    k_scan_apply<<<dim3(64, NB, 4), 256, 0, stream>>>(gA, part, wkb);

    k_scores<<<dim3(528, NB), 256, 0, stream>>>(qb, wkb, scores, denom);

    k_num<<<dim3(8, 32, NB), 256, 0, stream>>>(scores, vT, denom, out);
}

// Round 2
// 546.590 us; speedup vs baseline: 1.0234x; 1.0234x over previous
//
#include <hip/hip_runtime.h>

typedef unsigned short u16;
typedef unsigned int u32;

typedef __bf16 bf16x8 __attribute__((ext_vector_type(8)));
typedef float f32x4 __attribute__((ext_vector_type(4)));
typedef u16 u16x8 __attribute__((ext_vector_type(8)));

#define TSEQ 4096
#define DDIM 1024
#define NB 4
#define EPSV 1e-6f
// bounce-buffer row pitch in u16 (272 B = 17*16 -> rows stay 16B-aligned, banks rotate)
#define CPITCH 136
// 256^2 epilogue bounce pitch (u16): 528 B rows, 16B-aligned, banks rotate by 4
#define EPITCH 264

__device__ __forceinline__ u16 f2b(float f) {
    union { float f; u32 u; } v; v.f = f;
    u32 r = v.u + 0x7FFFu + ((v.u >> 16) & 1u);
    return (u16)(r >> 16);
}
__device__ __forceinline__ float b2f(u16 h) {
    union { u32 u; float f; } v; v.u = ((u32)h) << 16; return v.f;
}
__device__ __forceinline__ u16 f2h(float f) {
    union { _Float16 h; u16 u; } v; v.h = (_Float16)f; return v.u;
}
__device__ __forceinline__ float h2f(u16 u) {
    union { u16 u; _Float16 h; } v; v.u = u; return (float)v.h;
}

// ---------------- merged prep: x->bf16, W->bf16 concat, bias concat, denom zero ----
__global__ __launch_bounds__(256) void k_prep(
    const float* __restrict__ x,
    const float* __restrict__ wq, const float* __restrict__ wk,
    const float* __restrict__ wv, const float* __restrict__ wa,
    const float* __restrict__ bq, const float* __restrict__ bk,
    const float* __restrict__ bv, const float* __restrict__ ba,
    u16* __restrict__ xw, u16* __restrict__ wcat, float* __restrict__ bcat,
    float* __restrict__ denom) {
    int bid = blockIdx.x, tid = threadIdx.x;
    if (bid < 1024) {
        size_t base = (size_t)bid * 4096 + tid;
#pragma unroll
        for (int k = 0; k < 16; ++k) {
            size_t f4 = base + k * 256;
            float4 f = ((const float4*)x)[f4];
            ushort4 u;
            u.x = f2b(f.x); u.y = f2b(f.y); u.z = f2b(f.z); u.w = f2b(f.w);
            *(ushort4*)(xw + f4 * 4) = u;
        }
    } else if (bid < 1280) {
        size_t base = (size_t)(bid - 1024) * 4096 + tid;
#pragma unroll
        for (int k = 0; k < 16; ++k) {
            size_t f4 = base + k * 256;
            int sel = (int)(f4 >> 18);
            const float* src = (sel == 0) ? wq : (sel == 1) ? wk : (sel == 2) ? wv : wa;
            float4 f = ((const float4*)src)[f4 & 262143];
            ushort4 u;
            u.x = f2b(f.x); u.y = f2b(f.y); u.z = f2b(f.z); u.w = f2b(f.w);
            *(ushort4*)(wcat + f4 * 4) = u;
        }
    } else if (bid == 1280) {
#pragma unroll
        for (int c = 0; c < 16; ++c) {
            int j = c * 256 + tid;
            int sel = j >> 10;
            const float* src = (sel == 0) ? bq : (sel == 1) ? bk : (sel == 2) ? bv : ba;
            bcat[j] = src[j & 1023];
        }
    } else {
        float4 z = {0.f, 0.f, 0.f, 0.f};
#pragma unroll
        for (int k = 0; k < 16; ++k)
            ((float4*)denom)[k * 256 + tid] = z;
    }
}

// ---------------- GEMM core helpers (used by k_scores / k_num, 128^2 structure) ----
__device__ __forceinline__ void stage_k(u16* __restrict__ dst, const char* __restrict__ base,
                                        int ld2, int kbyte, int wid, int lane) {
#pragma unroll
    for (int c = 0; c < 4; ++c) {
        const char* g = base + c * 8 * ld2 + kbyte;
        char* l = (char*)dst + (wid * 32 + c * 8) * 128 + lane * 16;
        __builtin_amdgcn_global_load_lds((const __attribute__((address_space(1))) u32*)g,
                                         (__attribute__((address_space(3))) u32*)l, 16, 0, 0);
    }
}

__device__ __forceinline__ void mma_tile(const u16* __restrict__ As, const u16* __restrict__ Bs,
                                         f32x4 acc[4][4], int wm, int wn, int quad, int l15) {
#pragma unroll
    for (int kk = 0; kk < 64; kk += 32) {
        int cg = (kk >> 3) + quad;
        bf16x8 a[4], b[4];
#pragma unroll
        for (int i = 0; i < 4; ++i) {
            int arow = wm * 64 + i * 16 + l15;
            int brow = wn * 64 + i * 16 + l15;
            a[i] = *(const bf16x8*)(As + arow * 64 + ((cg ^ (arow & 7)) << 3));
            b[i] = *(const bf16x8*)(Bs + brow * 64 + ((cg ^ (brow & 7)) << 3));
        }
#pragma unroll
        for (int i = 0; i < 4; ++i)
#pragma unroll
            for (int j = 0; j < 4; ++j)
                acc[i][j] = __builtin_amdgcn_mfma_f32_16x16x32_bf16(a[i], b[j], acc[i][j], 0, 0, 0);
    }
}

// ---------------- fused QKVA projection GEMM: 256^2 tile, 8-wave, 8-phase ----------
// Round 13: read-once fragment ledger. Round 12's phases re-read operand frags
// per quadrant (48 ds_read_b128/K-tile/wave); LDS pipe arithmetic showed that to
// be the binding resource (MfmaUtil pinned at 27%). Now each fragment is read
// ONCE per K-tile (24/wave = (128+64)*64*2B / 1KB floor): A-half cached in Ar
// (overwritten at ph2), B both halves cached in Br for the whole tile.
//   ph0: LDA(h0) 8 + LDB(h0) 4 -> MFMA quadrant (0,0)
//   ph1: LDB(h1) 4             -> (0,1)   (Ar = A-h0)
//   ph2: LDA(h1) 8 (overwrite) -> (1,1)   (Br[1] live)
//   ph3: 0 reads               -> (1,0)   (Ar = A-h1, Br[0] live since ph0)
// Stage/barrier/vmcnt ledger identical to round 12 (verified): q0->A[t+1]h1,
// q1->B[t+1]h1, q2->A[t+2]h0, q3->B[t+2]h0 + vmcnt(4). Never vmcnt(0) in loop.
#define STG_A(d, h, t) do { \
    const char* _g = gAp + ((h) * 262144 + wid * 32768 + (t) * 128); \
    char* _l = lA + ((d) * 32768 + (h) * 16384); \
    __builtin_amdgcn_global_load_lds((const __attribute__((address_space(1))) u32*)_g, \
        (__attribute__((address_space(3))) u32*)_l, 16, 0, 0); \
    __builtin_amdgcn_global_load_lds((const __attribute__((address_space(1))) u32*)(_g + 16384), \
        (__attribute__((address_space(3))) u32*)(_l + 1024), 16, 0, 0); \
  } while (0)

#define STG_B(d, h, t) do { \
    const char* _g = gBp + ((h) * 262144 + wid * 32768 + (t) * 128); \
    char* _l = lB + ((d) * 32768 + (h) * 16384); \
    __builtin_amdgcn_global_load_lds((const __attribute__((address_space(1))) u32*)_g, \
        (__attribute__((address_space(3))) u32*)_l, 16, 0, 0); \
    __builtin_amdgcn_global_load_lds((const __attribute__((address_space(1))) u32*)(_g + 16384), \
        (__attribute__((address_space(3))) u32*)(_l + 1024), 16, 0, 0); \
  } while (0)

#define NOP_ ((void)0)
#define VM4_ asm volatile("s_waitcnt vmcnt(4)" ::: "memory")
#define VM0_ asm volatile("s_waitcnt vmcnt(0)" ::: "memory")
#define BAR_ __builtin_amdgcn_s_barrier()
#define LGK_ asm volatile("s_waitcnt lgkmcnt(0)" ::: "memory")

// 8 ds_read_b128 -> Ar (one 2-half K-slice pair per m-frag)
#define LDA(hh, dd) do { \
    const u16* _Ah = As + (dd) * 16384 + (hh) * 8192; \
    _Pragma("unroll") \
    for (int _i = 0; _i < 4; ++_i) { \
      int _ra = wm * 64 + _i * 16 + l15; \
      const u16* _p = _Ah + _ra * 64; \
      Ar[_i][0] = *(const bf16x8*)(_p + ((quad ^ (_ra & 7)) << 3)); \
      Ar[_i][1] = *(const bf16x8*)(_p + (((quad + 4) ^ (_ra & 7)) << 3)); \
    } } while (0)

// 4 ds_read_b128 -> Br[hh]
#define LDB(hh, dd) do { \
    const u16* _Bh = Bs + (dd) * 16384 + (hh) * 8192; \
    _Pragma("unroll") \
    for (int _j = 0; _j < 2; ++_j) { \
      int _rb = wn * 32 + _j * 16 + l15; \
      const u16* _p = _Bh + _rb * 64; \
      Br[hh][_j][0] = *(const bf16x8*)(_p + ((quad ^ (_rb & 7)) << 3)); \
      Br[hh][_j][1] = *(const bf16x8*)(_p + (((quad + 4) ^ (_rb & 7)) << 3)); \
    } } while (0)

// 16 MFMA: C-quadrant (qa,qb) over BK=64 (Ar holds A-half, Br[qb] the B-half)
#define MMA(qa, qb) do { \
    __builtin_amdgcn_s_setprio(1); \
    _Pragma("unroll") \
    for (int _kk = 0; _kk < 2; ++_kk) \
      _Pragma("unroll") \
      for (int _i = 0; _i < 4; ++_i) \
        _Pragma("unroll") \
        for (int _j = 0; _j < 2; ++_j) \
          acc[(qa) * 4 + _i][(qb) * 2 + _j] = __builtin_amdgcn_mfma_f32_16x16x32_bf16( \
              Ar[_i][_kk], Br[qb][_j][_kk], acc[(qa) * 4 + _i][(qb) * 2 + _j], 0, 0, 0); \
    __builtin_amdgcn_s_setprio(0); \
  } while (0)

__global__ __launch_bounds__(512, 2) void k_gemm_qkva(
    const u16* __restrict__ xw, const u16* __restrict__ wcat, const float* __restrict__ bcat,
    u16* __restrict__ qb, u16* __restrict__ kb, u16* __restrict__ vT, u16* __restrict__ gA,
    float* __restrict__ part) {
    __shared__ __align__(16) char smem[131072];  // A[2][2][128][64] | B[2][2][128][64]
    u16* As = (u16*)smem;
    u16* Bs = (u16*)(smem + 65536);
    int tid = threadIdx.x;
    int wid = tid >> 6, lane = tid & 63;
    int wm = wid >> 2, wn = wid & 3;          // 2 x 4 wave grid
    int quad = lane >> 4, l15 = lane & 15;
    int g8 = lane >> 3, hx = (lane & 7) ^ g8;
    size_t m0 = (size_t)blockIdx.x * 256, n0 = (size_t)blockIdx.y * 256;  // m fastest (XCD pin)
    const char* gAp = (const char*)xw + (m0 + g8) * 2048 + hx * 16;
    const char* gBp = (const char*)wcat + (n0 + g8) * 2048 + hx * 16;
    char* lA = smem + wid * 2048 + lane * 16;
    char* lB = smem + 65536 + wid * 2048 + lane * 16;

    f32x4 acc[8][4] = {};
    bf16x8 Ar[4][2];      // current A-half frags (32 VGPR)
    bf16x8 Br[2][2][2];   // both B-half frags, live across the tile (32 VGPR)

    // prologue: tile0 fully + tile1 h0 halves (12 loads); vmcnt(4) -> tile0 landed,
    // {A1h0,B1h0} in flight == steady-state invariant.
    STG_A(0, 0, 0); STG_A(0, 1, 0);
    STG_B(0, 0, 0); STG_B(0, 1, 0);
    STG_A(1, 0, 1); STG_B(1, 0, 1);
    VM4_;
    BAR_;

#pragma unroll 2
    for (int t = 0; t < 14; ++t) {
        int d = t & 1, dn = d ^ 1;
        // ph0
        LDA(0, d); LDB(0, d);
        STG_A(dn, 1, t + 1);
        BAR_; LGK_; MMA(0, 0); BAR_;
        // ph1
        LDB(1, d);
        STG_B(dn, 1, t + 1);
        BAR_; LGK_; MMA(0, 1); BAR_;
        // ph2
        LDA(1, d);
        STG_A(d, 0, t + 2);
        BAR_; LGK_; MMA(1, 1); BAR_;
        // ph3 (no reads; Br[0] from ph0, Ar from ph2)
        STG_B(d, 0, t + 2);
        BAR_; MMA(1, 0); VM4_; BAR_;
    }
    // t = 14 (tail: no t+2 stages; drain so tile 15 is resident)
    {
        LDA(0, 0); LDB(0, 0);
        STG_A(1, 1, 15);
        BAR_; LGK_; MMA(0, 0); BAR_;
        LDB(1, 0);
        STG_B(1, 1, 15);
        BAR_; LGK_; MMA(0, 1); BAR_;
        LDA(1, 0);
        BAR_; LGK_; MMA(1, 1); BAR_;
        BAR_; MMA(1, 0); VM0_; BAR_;
    }
    // t = 15 (no stages in flight)
    {
        LDA(0, 1); LDB(0, 1);
        BAR_; LGK_; MMA(0, 0); BAR_;
        LDB(1, 1);
        BAR_; LGK_; MMA(0, 1); BAR_;
        LDA(1, 1);
        BAR_; LGK_; MMA(1, 1); BAR_;
        BAR_; MMA(1, 0); BAR_;
    }

    // ---------------- epilogue: two 128-row bounce rounds through LDS -------------
    int blk = (int)(n0 >> 10), nf0 = (int)(n0 & 1023);
    int bB = (int)(m0 >> 12), t0m = (int)(m0 & 4095);
    float bias[4];
#pragma unroll
    for (int j = 0; j < 4; ++j)
        bias[j] = bcat[n0 + (size_t)((j >> 1) * 128 + wn * 32 + (j & 1) * 16 + l15)];
    u16* Cs = (u16*)smem;

#pragma unroll
    for (int h = 0; h < 2; ++h) {
        if (h) __syncthreads();  // prior round's LDS reads done before overwrite
#pragma unroll
        for (int j = 0; j < 4; ++j) {
            float cs = 0.f;
            int col = (j >> 1) * 128 + wn * 32 + (j & 1) * 16 + l15;
#pragma unroll
            for (int i4 = 0; i4 < 4; ++i4) {
#pragma unroll
                for (int r = 0; r < 4; ++r) {
                    float z = acc[h * 4 + i4][j][r] + bias[j];
                    u16 o;
                    if (blk < 2) {
                        o = f2b(fmaxf(z, 0.f));
                    } else if (blk == 2) {
                        o = f2b(z);
                    } else {
                        float gg = __logf(1.f / (1.f + __expf(-z)) + 1e-6f);
                        o = f2h(gg);
                        cs += gg;
                    }
                    Cs[(wm * 64 + i4 * 16 + quad * 4 + r) * EPITCH + col] = o;
                }
            }
            if (blk == 3) {
                // 64-row chunk column sum (rows h*128 + wm*64 .. +63)
                cs += __shfl_xor(cs, 16, 64);
                cs += __shfl_xor(cs, 32, 64);
                if (quad == 0) {
                    int chunk = (t0m >> 6) + h * 2 + wm;
                    part[((size_t)(bB * 64 + chunk) << 10) + nf0 + col] = cs;
                }
            }
        }
        __syncthreads();
        if (blk != 2) {
            // row-major vectorized store (q / k / gA)
            u16* dst = (blk == 0) ? qb : (blk == 1) ? kb : gA;
            int lr = tid >> 2, c0 = (tid & 3) * 64;
            size_t rowo = (size_t)(m0 + h * 128 + lr) * 1024 + nf0 + c0;
#pragma unroll
            for (int i = 0; i < 8; ++i)
                *(u16x8*)(dst + rowo + i * 8) = *(const u16x8*)(Cs + lr * EPITCH + c0 + i * 8);
        } else {
            // v: read bounce transposed, write vT[b][j][t] coalesced.
            int jc = tid >> 1, th = (tid & 1) * 64;
            size_t rowo = (((size_t)(bB * 1024 + nf0 + jc)) << 12) + t0m + h * 128 + th;
#pragma unroll
            for (int i = 0; i < 8; ++i) {
                u16x8 vv;
#pragma unroll
                for (int e = 0; e < 8; ++e)
                    vv[e] = Cs[(th + i * 8 + e) * EPITCH + jc];
                *(u16x8*)(vT + rowo + i * 8) = vv;
            }
        }
    }
}

// ---------------- gate scan apply (fused suffix-sum of raw chunk partials) ----------
__global__ __launch_bounds__(256) void k_scan_apply(
    const u16* __restrict__ gA, const float* __restrict__ part, u16* __restrict__ kb) {
    int c = blockIdx.x, b = blockIdx.y;
    int col = blockIdx.z * 256 + threadIdx.x;
    float r = 0.f;
    for (int c2 = c + 1; c2 < 64; ++c2)
        r += part[((size_t)(b * 64 + c2) << 10) + col];
    size_t base = (((size_t)(b * TSEQ + c * 64)) << 10) + col;
#pragma unroll 4
    for (int s = 63; s >= 0; --s) {
        size_t ro = base + ((size_t)s << 10);
        r += h2f(gA[ro]);
        kb[ro] = f2b(b2f(kb[ro]) * __expf(r));
    }
}

// ---------------- scores = q @ wk^T (causal), bf16 out + denom atomics ----------------
__global__ __launch_bounds__(256) void k_scores(
    const u16* __restrict__ qb, const u16* __restrict__ wkb,
    u16* __restrict__ scores, float* __restrict__ denom) {
    int bid = blockIdx.x, b = blockIdx.y;
    int xc = bid & 7, idx = bid >> 3;          // idx in [0, 66)
    int rs0 = xc, rs1 = 15 - xc, rs2 = 16 + xc, rs3 = 31 - xc;  // ascending
    int si = 0, rem = idx;
    for (; si < 32; ++si) {
        int n = (rs0 >= si) + (rs1 >= si) + (rs2 >= si) + (rs3 >= si);
        if (rem < n) break;
        rem -= n;
    }
    int ti = rs3, cnt = 0;
    if (rs0 >= si) { if (cnt == rem) ti = rs0; ++cnt; }
    if (rs1 >= si) { if (cnt == rem) ti = rs1; ++cnt; }
    if (rs2 >= si) { if (cnt == rem) ti = rs2; ++cnt; }
    if (rs3 >= si) { if (cnt == rem) ti = rs3; ++cnt; }
    __shared__ __align__(16) char smem[CPITCH * 128 * 2];
    u16* As = (u16*)smem;
    u16* Bs = (u16*)(smem + 16384);
    int tid = threadIdx.x;
    const u16* A = qb + ((size_t)b << 22);
    const u16* Bm = wkb + ((size_t)b << 22);
    int t0 = ti * 128, s0 = si * 128;
    int wid = tid >> 6, lane = tid & 63;
    int wm = wid >> 1, wn = wid & 1, quad = lane >> 4, l15 = lane & 15;
    int hxor = (lane & 7) ^ (lane >> 3);
    const char* baA = (const char*)A + (size_t)(t0 + wid * 32 + (lane >> 3)) * 2048 + hxor * 16;
    const char* baB = (const char*)Bm + (size_t)(s0 + wid * 32 + (lane >> 3)) * 2048 + hxor * 16;
    f32x4 acc[4][4] = {};
#pragma unroll
    for (int k0 = 0; k0 < DDIM; k0 += 64) {
        stage_k(As, baA, 2048, k0 * 2, wid, lane);
        stage_k(Bs, baB, 2048, k0 * 2, wid, lane);
        __syncthreads();
        mma_tile(As, Bs, acc, wm, wn, quad, l15);
        __syncthreads();
    }
    u16* Cs = (u16*)smem;
#pragma unroll
    for (int im = 0; im < 4; ++im) {
#pragma unroll
        for (int r = 0; r < 4; ++r) {
            int trow = t0 + wm * 64 + im * 16 + quad * 4 + r;
            float rs = 0.f;
#pragma unroll
            for (int jn = 0; jn < 4; ++jn) {
                int s = s0 + wn * 64 + jn * 16 + l15;
                float val = acc[im][jn][r];
                if (s > trow) val = 0.f;
                rs += val;
                Cs[(wm * 64 + im * 16 + quad * 4 + r) * CPITCH + wn * 64 + jn * 16 + l15] = f2b(val);
            }
#pragma unroll
            for (int m = 1; m < 16; m <<= 1) rs += __shfl_xor(rs, m, 64);
            if (l15 == 0) atomicAdd(denom + (b << 12) + trow, rs);
        }
    }
    __syncthreads();
    int r = tid >> 1, ch = (tid & 1) * 64;
    size_t rowo = ((size_t)(b * TSEQ + t0 + r) << 12) + s0 + ch;
#pragma unroll
    for (int i = 0; i < 8; ++i)
        *(u16x8*)(scores + rowo + i * 8) = *(const u16x8*)(Cs + r * CPITCH + ch + i * 8);
}

// ---------------- num = scores @ v (causal K bound), divide by denom ----------------
__global__ __launch_bounds__(256) void k_num(
    const u16* __restrict__ scores, const u16* __restrict__ vT,
    const float* __restrict__ denom, float* __restrict__ out) {
    int ji = blockIdx.x, ti = 31 - blockIdx.y, b = blockIdx.z;
    __shared__ __align__(16) u16 As[128 * 64];
    __shared__ __align__(16) u16 Bs[128 * 64];
    int tid = threadIdx.x;
    const u16* A = scores + ((size_t)b << 24);  // [T][T]
    const u16* Bm = vT + ((size_t)b << 22);     // [D][T]
    int t0 = ti * 128, j0 = ji * 128;
    int wid = tid >> 6, lane = tid & 63;
    int wm = wid >> 1, wn = wid & 1, quad = lane >> 4, l15 = lane & 15;
    int hxor = (lane & 7) ^ (lane >> 3);
    const char* pA = (const char*)A + (size_t)(t0 + wid * 32 + (lane >> 3)) * 8192 + hxor * 16;
    const char* pB = (const char*)Bm + (size_t)(j0 + wid * 32 + (lane >> 3)) * 8192 + hxor * 16;
    f32x4 acc[4][4] = {};
    int kmax = (ti + 1) * 128;  // multiple of 128 -> unroll-by-2 safe
    for (int k0 = 0; k0 < kmax; k0 += 128) {
        stage_k(As, pA, 8192, 0, wid, lane);
        stage_k(Bs, pB, 8192, 0, wid, lane);
        __syncthreads();
        mma_tile(As, Bs, acc, wm, wn, quad, l15);
        __syncthreads();
        stage_k(As, pA, 8192, 128, wid, lane);
        stage_k(Bs, pB, 8192, 128, wid, lane);
        __syncthreads();
        mma_tile(As, Bs, acc, wm, wn, quad, l15);
        __syncthreads();
        pA += 256; pB += 256;
    }
#pragma unroll
    for (int im = 0; im < 4; ++im) {
#pragma unroll
        for (int r = 0; r < 4; ++r) {
            int t = t0 + wm * 64 + im * 16 + quad * 4 + r;
            float den = denom[(b << 12) + t] + EPSV;
#pragma unroll
            for (int jn = 0; jn < 4; ++jn) {
                int j = j0 + wn * 64 + jn * 16 + l15;
                out[((size_t)(b * TSEQ + t) << 10) + j] = acc[im][jn][r] / den;
            }
        }
    }
}

// ---------------- workspace layout (bytes) ----------------
static const size_t OFF_Q      = 0;
static const size_t OFF_WK     = 33554432;
static const size_t OFF_VT     = 67108864;
static const size_t OFF_DENOM  = 100663296;
static const size_t OFF_BCAT   = 100728832;
static const size_t OFF_XW     = 100745216;
static const size_t OFF_WCAT   = 134299648;
static const size_t OFF_GA     = 176242688;   // f16: 33.5 MB
static const size_t OFF_PART   = 243351552;
static const size_t OFF_SCORES = OFF_XW;  // 134,217,728 B, overlays dead early region

extern "C" void kernel_launch(void* const* d_in, const int* in_sizes, int n_in,
                              void* d_out, int out_size, void* d_ws, size_t ws_size,
                              hipStream_t stream) {
    const float* x  = (const float*)d_in[0];
    const float* Wq = (const float*)d_in[1];
    const float* bq = (const float*)d_in[2];
    const float* Wk = (const float*)d_in[3];
    const float* bk = (const float*)d_in[4];
    const float* Wv = (const float*)d_in[5];
    const float* bv = (const float*)d_in[6];
    const float* Wa = (const float*)d_in[7];
    const float* ba = (const float*)d_in[8];
    float* out = (float*)d_out;

    char* W = (char*)d_ws;
    u16* qb      = (u16*)(W + OFF_Q);
    u16* wkb     = (u16*)(W + OFF_WK);
    u16* vT      = (u16*)(W + OFF_VT);
    float* denom = (float*)(W + OFF_DENOM);
    float* bcat  = (float*)(W + OFF_BCAT);
    u16* xw      = (u16*)(W + OFF_XW);
    u16* wcat    = (u16*)(W + OFF_WCAT);
    u16* gA      = (u16*)(W + OFF_GA);
    float* part  = (float*)(W + OFF_PART);
    u16* scores  = (u16*)(W + OFF_SCORES);

    k_prep<<<1282, 256, 0, stream>>>(x, Wq, Wk, Wv, Wa, bq, bk, bv, ba, xw, wcat, bcat, denom);

    k_gemm_qkva<<<dim3(64, 16), 512, 0, stream>>>(xw, wcat, bcat, qb, wkb, vT, gA, part);

    k_scan_apply<<<dim3(64, NB, 4), 256, 0, stream>>>(gA, part, wkb);

    k_scores<<<dim3(528, NB), 256, 0, stream>>>(qb, wkb, scores, denom);

    k_num<<<dim3(8, 32, NB), 256, 0, stream>>>(scores, vT, denom, out);
}